// Round 3
// baseline (1154.682 us; speedup 1.0000x reference)
//
#include <hip/hip_runtime.h>
#include <hip/hip_bf16.h>
#include <stdint.h>

typedef __attribute__((ext_vector_type(8))) short short8;
typedef __attribute__((ext_vector_type(4))) float floatx4;

__device__ __forceinline__ float bf2f(unsigned short u) {
    union { unsigned int ui; float f; } v; v.ui = ((unsigned int)u) << 16; return v.f;
}
__device__ __forceinline__ unsigned short f2bf(float f) {
    union { float f; unsigned int u; } v; v.f = f;
    unsigned int u = v.u;
    unsigned int r = (u + 0x7fffu + ((u >> 16) & 1u)) >> 16;
    return (unsigned short)r;
}

// ---------------- convert features fp32 -> bf16 ----------------
__global__ __launch_bounds__(256)
void convert_bf16(const float* __restrict__ in, unsigned short* __restrict__ out, int n4) {
    int i = blockIdx.x * blockDim.x + threadIdx.x;
    int stride = gridDim.x * blockDim.x;
    for (; i < n4; i += stride) {
        float4 v = ((const float4*)in)[i];
        ushort4 o;
        o.x = f2bf(v.x); o.y = f2bf(v.y); o.z = f2bf(v.z); o.w = f2bf(v.w);
        ((ushort4*)out)[i] = o;
    }
}

// ---------------- pack weights into B-fragment order ----------------
// Wp[kk][ks(2)][nt(4)][lane(64)][j(8)] = W[kk][cin = ks*32 + (lane>>4)*8 + j][cout = nt*16 + (lane&15)]
__global__ __launch_bounds__(256)
void pack_w(const float* __restrict__ W1, const float* __restrict__ W2,
            unsigned short* __restrict__ Wp1, unsigned short* __restrict__ Wp2) {
    int bi = blockIdx.x;               // 0..53
    const float* W = (bi < 27) ? W1 : W2;
    unsigned short* Wp = (bi < 27) ? Wp1 : Wp2;
    int kk = bi % 27;
    int t = threadIdx.x;
    int lane = t & 63, grp = t >> 6;
    int q = lane >> 4, l15 = lane & 15;
    for (int c8 = grp; c8 < 8; c8 += 4) {
        int ks = c8 >> 2, nt = c8 & 3;
        unsigned short* dst = Wp + (((kk*2 + ks)*4 + nt)*64 + lane)*8;
        const float* src = W + kk*4096 + (ks*32 + q*8)*64 + nt*16 + l15;
        #pragma unroll
        for (int j = 0; j < 8; ++j) dst[j] = f2bf(src[j*64]);
    }
}

// ---------------- gathered MFMA conv ----------------
// block = 256 threads = 4 waves; wave handles 64 voxels (4 subtiles of 16) x 64 out-ch.
template<int BN>
__global__ __launch_bounds__(256, 2)
void conv_kernel(const unsigned short* __restrict__ xin, const int* __restrict__ nbr,
                 const float* __restrict__ valid, const unsigned short* __restrict__ Wp,
                 const float* __restrict__ ab, unsigned short* __restrict__ yout, int nvox) {
    int t = threadIdx.x;
    int wave = t >> 6, lane = t & 63;
    int q = lane >> 4, l15 = lane & 15;
    int m0 = blockIdx.x * 256 + wave * 64;
    if (m0 >= nvox) return;

    bool inr[4]; int mb[4];
    #pragma unroll
    for (int s = 0; s < 4; ++s) { mb[s] = m0 + s*16; inr[s] = (mb[s] < nvox); }

    float a_[2][8], b_[2][8];
    if (BN) {
        #pragma unroll
        for (int ks = 0; ks < 2; ++ks)
            #pragma unroll
            for (int j = 0; j < 8; ++j) {
                int c = ks*32 + q*8 + j;
                a_[ks][j] = ab[c];
                b_[ks][j] = ab[64 + c];
            }
    }

    floatx4 acc[4][4];
    #pragma unroll
    for (int s = 0; s < 4; ++s)
        #pragma unroll
        for (int nt = 0; nt < 4; ++nt) acc[s][nt] = (floatx4){0.f, 0.f, 0.f, 0.f};

    for (int kk = 0; kk < 27; ++kk) {
        int base = kk * nvox;
        int idx[4]; float vld[4];
        #pragma unroll
        for (int s = 0; s < 4; ++s) {
            if (inr[s]) {
                idx[s] = nbr[base + mb[s] + l15];
                vld[s] = valid[base + mb[s] + l15];
            } else { idx[s] = 0; vld[s] = 0.f; }
        }
        #pragma unroll
        for (int ks = 0; ks < 2; ++ks) {
            short8 av[4];
            #pragma unroll
            for (int s = 0; s < 4; ++s) {
                short8 a = (short8)0;
                if (vld[s] != 0.f) {
                    a = *(const short8*)(xin + (size_t)idx[s]*64 + ks*32 + q*8);
                    if (BN) {
                        #pragma unroll
                        for (int j = 0; j < 8; ++j) {
                            float f = bf2f((unsigned short)a[j]);
                            f = fmaxf(a_[ks][j]*f + b_[ks][j], 0.f);
                            a[j] = (short)f2bf(f);
                        }
                    }
                }
                av[s] = a;
            }
            const unsigned short* wb = Wp + ((kk*2 + ks)*4)*512 + lane*8;
            #pragma unroll
            for (int nt = 0; nt < 4; ++nt) {
                short8 bv = *(const short8*)(wb + nt*512);
                #pragma unroll
                for (int s = 0; s < 4; ++s)
                    acc[s][nt] = __builtin_amdgcn_mfma_f32_16x16x32_bf16(av[s], bv, acc[s][nt], 0, 0, 0);
            }
        }
    }

    // D layout: col = lane&15 (out-ch within 16), row = (lane>>4)*4 + reg (voxel within 16)
    #pragma unroll
    for (int s = 0; s < 4; ++s) {
        if (!inr[s]) continue;
        int rowb = mb[s] + q*4;
        #pragma unroll
        for (int r = 0; r < 4; ++r) {
            unsigned short* yo = yout + (size_t)(rowb + r)*64 + l15;
            #pragma unroll
            for (int nt = 0; nt < 4; ++nt)
                yo[nt*16] = f2bf(acc[s][nt][r]);
        }
    }
}

// ---------------- per-channel sum / sumsq ----------------
__global__ __launch_bounds__(256)
void stats_kernel(const unsigned short* __restrict__ y, float* __restrict__ sums, int nvox) {
    int t = threadIdx.x;
    int cp = t & 31, g = t >> 5;
    float s0 = 0, s1 = 0, q0 = 0, q1 = 0;
    for (int r = blockIdx.x*8 + g; r < nvox; r += gridDim.x*8) {
        unsigned int v = *(const unsigned int*)(y + (size_t)r*64 + cp*2);
        float f0 = bf2f((unsigned short)(v & 0xffffu));
        float f1 = bf2f((unsigned short)(v >> 16));
        s0 += f0; s1 += f1; q0 += f0*f0; q1 += f1*f1;
    }
    __shared__ float lds[256][4];
    lds[t][0] = s0; lds[t][1] = s1; lds[t][2] = q0; lds[t][3] = q1;
    __syncthreads();
    // thread t < 64 owns channel t: partials live at lds[gg*32 + (t>>1)][(t&1)] (sum)
    // and lds[gg*32 + (t>>1)][2+(t&1)] (sumsq), gg = 0..7.  (Round-2 bug: t<128 read OOB.)
    if (t < 64) {
        int cpp = t >> 1, par = t & 1;
        float s = 0, qq = 0;
        #pragma unroll
        for (int gg = 0; gg < 8; ++gg) {
            s  += lds[gg*32 + cpp][par];
            qq += lds[gg*32 + cpp][2 + par];
        }
        atomicAdd(&sums[t], s);
        atomicAdd(&sums[64 + t], qq);
    }
}

// ---------------- BN scale/bias ----------------
__global__ void finalize_kernel(const float* __restrict__ sums, const float* __restrict__ gamma,
                                const float* __restrict__ beta, float* __restrict__ ab, float invn) {
    int c = threadIdx.x;
    if (c < 64) {
        float mean = sums[c] * invn;
        float var  = sums[64 + c] * invn - mean*mean;
        float a = gamma[c] * rsqrtf(var + 1e-5f);
        ab[c] = a;
        ab[64 + c] = beta[c] - mean * a;
    }
}

// ---------------- epilogue: BN2 + identity + relu -> fp32 ----------------
__global__ __launch_bounds__(256)
void final_kernel(const unsigned short* __restrict__ y2, const float* __restrict__ feat,
                  const float* __restrict__ ab, float* __restrict__ out, int ntot2) {
    int i = blockIdx.x * blockDim.x + threadIdx.x;
    int stride = gridDim.x * blockDim.x;
    for (; i < ntot2; i += stride) {
        unsigned int v = ((const unsigned int*)y2)[i];
        int c0 = (i*2) & 63;
        float2 f = ((const float2*)feat)[i];
        float r0 = fmaxf(ab[c0]   * bf2f((unsigned short)(v & 0xffffu)) + ab[64 + c0]   + f.x, 0.f);
        float r1 = fmaxf(ab[c0+1] * bf2f((unsigned short)(v >> 16))     + ab[64 + c0+1] + f.y, 0.f);
        ((float2*)out)[i] = make_float2(r0, r1);
    }
}

extern "C" void kernel_launch(void* const* d_in, const int* in_sizes, int n_in,
                              void* d_out, int out_size, void* d_ws, size_t ws_size,
                              hipStream_t stream) {
    const float* features = (const float*)d_in[0];
    const int*   nbr      = (const int*)d_in[1];
    const float* valid    = (const float*)d_in[2];
    const float* W1       = (const float*)d_in[3];
    const float* gamma1   = (const float*)d_in[4];
    const float* beta1    = (const float*)d_in[5];
    const float* W2       = (const float*)d_in[6];
    const float* gamma2   = (const float*)d_in[7];
    const float* beta2    = (const float*)d_in[8];
    float* out = (float*)d_out;

    int nvox = in_sizes[0] / 64;           // 500000
    size_t featB = (size_t)nvox * 64 * 2;  // bf16 bytes per feature map (64 MB)

    // d_out doubles as scratch until the final kernel overwrites all of it:
    //   [0, featB)        xb  (bf16 features)
    //   [featB, 2*featB)  y1  (conv1 raw output, bf16)
    char* ob = (char*)d_out;
    unsigned short* xb = (unsigned short*)ob;
    unsigned short* y1 = (unsigned short*)(ob + featB);

    // d_ws (needs only ~64.5 MB):
    //   [0, 2KB)    stats   (sums1, sums2, ab1, ab2)
    //   [4KB, ..)   Wp1, Wp2 (packed bf16 weights, 216 KB each)
    //   [512KB, +featB) y2 (conv2 raw output, bf16)
    char* ws = (char*)d_ws;
    float* stats = (float*)ws;
    float* sums1 = stats;          // 128 floats
    float* sums2 = stats + 128;    // 128 floats
    float* ab1   = stats + 256;    // 128 floats
    float* ab2   = stats + 384;    // 128 floats
    unsigned short* Wp1 = (unsigned short*)(ws + 4096);
    unsigned short* Wp2 = (unsigned short*)(ws + 4096 + 221184);
    unsigned short* y2  = (unsigned short*)(ws + 524288);

    hipMemsetAsync(stats, 0, 512 * sizeof(float), stream);
    convert_bf16<<<2048, 256, 0, stream>>>(features, xb, nvox * 16);
    pack_w<<<54, 256, 0, stream>>>(W1, W2, Wp1, Wp2);

    int convGrid = (nvox + 255) / 256;
    conv_kernel<0><<<convGrid, 256, 0, stream>>>(xb, nbr, valid, Wp1, nullptr, y1, nvox);
    stats_kernel<<<256, 256, 0, stream>>>(y1, sums1, nvox);
    finalize_kernel<<<1, 64, 0, stream>>>(sums1, gamma1, beta1, ab1, 1.0f / nvox);
    conv_kernel<1><<<convGrid, 256, 0, stream>>>(y1, nbr, valid, Wp2, ab1, y2, nvox);
    stats_kernel<<<256, 256, 0, stream>>>(y2, sums2, nvox);
    finalize_kernel<<<1, 64, 0, stream>>>(sums2, gamma2, beta2, ab2, 1.0f / nvox);
    final_kernel<<<4096, 256, 0, stream>>>(y2, features, ab2, out, nvox * 32);
}

// Round 4
// 780.020 us; speedup vs baseline: 1.4803x; 1.4803x over previous
//
#include <hip/hip_runtime.h>
#include <hip/hip_bf16.h>
#include <stdint.h>

typedef __attribute__((ext_vector_type(8))) short short8;
typedef __attribute__((ext_vector_type(4))) float floatx4;

__device__ __forceinline__ float bf2f(unsigned short u) {
    union { unsigned int ui; float f; } v; v.ui = ((unsigned int)u) << 16; return v.f;
}
__device__ __forceinline__ unsigned short f2bf(float f) {
    union { float f; unsigned int u; } v; v.f = f;
    unsigned int u = v.u;
    unsigned int r = (u + 0x7fffu + ((u >> 16) & 1u)) >> 16;
    return (unsigned short)r;
}

// ---------------- convert features fp32 -> bf16 ----------------
__global__ __launch_bounds__(256)
void convert_bf16(const float* __restrict__ in, unsigned short* __restrict__ out, int n4) {
    int i = blockIdx.x * blockDim.x + threadIdx.x;
    int stride = gridDim.x * blockDim.x;
    for (; i < n4; i += stride) {
        float4 v = ((const float4*)in)[i];
        ushort4 o;
        o.x = f2bf(v.x); o.y = f2bf(v.y); o.z = f2bf(v.z); o.w = f2bf(v.w);
        ((ushort4*)out)[i] = o;
    }
}

// ---------------- encode: enc[k][i] = valid ? idx : -1, padded to nvoxp ----------------
__global__ __launch_bounds__(256)
void encode_kernel(const int* __restrict__ nbr, const float* __restrict__ valid,
                   int* __restrict__ enc, int nvox, int nvoxp) {
    int k = blockIdx.y;
    int r = blockIdx.x * 256 + threadIdx.x;
    int v = -1;
    if (r < nvox) {
        float f = valid[(size_t)k * nvox + r];
        int ix = nbr[(size_t)k * nvox + r];
        v = (f != 0.f) ? ix : -1;
    }
    enc[(size_t)k * nvoxp + r] = v;
}

// ---------------- pack weights into B-fragment order ----------------
// Wp[kk][ks(2)][nt(4)][lane(64)][j(8)] = W[kk][cin = ks*32 + (lane>>4)*8 + j][cout = nt*16 + (lane&15)]
__global__ __launch_bounds__(256)
void pack_w(const float* __restrict__ W1, const float* __restrict__ W2,
            unsigned short* __restrict__ Wp1, unsigned short* __restrict__ Wp2) {
    int bi = blockIdx.x;               // 0..53
    const float* W = (bi < 27) ? W1 : W2;
    unsigned short* Wp = (bi < 27) ? Wp1 : Wp2;
    int kk = bi % 27;
    int t = threadIdx.x;
    int lane = t & 63, grp = t >> 6;
    int q = lane >> 4, l15 = lane & 15;
    for (int c8 = grp; c8 < 8; c8 += 4) {
        int ks = c8 >> 2, nt = c8 & 3;
        unsigned short* dst = Wp + (((kk*2 + ks)*4 + nt)*64 + lane)*8;
        const float* src = W + kk*4096 + (ks*32 + q*8)*64 + nt*16 + l15;
        #pragma unroll
        for (int j = 0; j < 8; ++j) dst[j] = f2bf(src[j*64]);
    }
}

// ---------------- gathered MFMA conv (branchless, fused per-channel stats) ----------------
// block = 256 = 4 waves; wave: 64 voxels (4 subtiles of 16) x 64 out-ch.
__global__ __launch_bounds__(256, 4)
void conv_kernel(const unsigned short* __restrict__ xin, const int* __restrict__ enc,
                 const unsigned short* __restrict__ Wp, const unsigned short* __restrict__ zrow,
                 unsigned short* __restrict__ yout, float* __restrict__ sums,
                 int nvox, int nvoxp) {
    int t = threadIdx.x;
    int wave = t >> 6, lane = t & 63;
    int q = lane >> 4, l15 = lane & 15;
    int m0 = blockIdx.x * 256 + wave * 64;   // < nvoxp always (grid covers pad)

    floatx4 acc[4][4];
    #pragma unroll
    for (int s = 0; s < 4; ++s)
        #pragma unroll
        for (int nt = 0; nt < 4; ++nt) acc[s][nt] = (floatx4){0.f, 0.f, 0.f, 0.f};

    for (int kk = 0; kk < 27; ++kk) {
        // one coalesced load: lane holds enc for voxel m0+lane; distribute via bpermute
        int e_all = enc[(size_t)kk * nvoxp + m0 + lane];
        const unsigned short* rp[4];
        #pragma unroll
        for (int s = 0; s < 4; ++s) {
            int es = __builtin_amdgcn_ds_bpermute((s*16 + l15) * 4, e_all);
            rp[s] = (es >= 0) ? (xin + (size_t)es * 64) : zrow;   // zero page: A-row = 0
        }
        // issue all 8 gathers up front (branchless -> pipelineable)
        short8 av[2][4];
        #pragma unroll
        for (int ks = 0; ks < 2; ++ks)
            #pragma unroll
            for (int s = 0; s < 4; ++s)
                av[ks][s] = *(const short8*)(rp[s] + ks*32 + q*8);

        #pragma unroll
        for (int ks = 0; ks < 2; ++ks) {
            const unsigned short* wb = Wp + ((kk*2 + ks)*4)*512 + lane*8;
            #pragma unroll
            for (int nt = 0; nt < 4; ++nt) {
                short8 bv = *(const short8*)(wb + nt*512);
                #pragma unroll
                for (int s = 0; s < 4; ++s)
                    acc[s][nt] = __builtin_amdgcn_mfma_f32_16x16x32_bf16(av[ks][s], bv, acc[s][nt], 0, 0, 0);
            }
        }
    }

    // store: D layout col = lane&15, row = q*4 + reg
    #pragma unroll
    for (int s = 0; s < 4; ++s) {
        int rowb = m0 + s*16 + q*4;
        #pragma unroll
        for (int r = 0; r < 4; ++r) {
            if (rowb + r < nvox) {
                unsigned short* yo = yout + (size_t)(rowb + r)*64 + l15;
                #pragma unroll
                for (int nt = 0; nt < 4; ++nt)
                    yo[nt*16] = f2bf(acc[s][nt][r]);
            }
        }
    }

    // fused per-channel stats (pad rows have acc == 0: every tap hit the zero page)
    __shared__ float sred[128];
    if (t < 128) sred[t] = 0.f;
    __syncthreads();
    #pragma unroll
    for (int nt = 0; nt < 4; ++nt) {
        float s_ = 0.f, q_ = 0.f;
        #pragma unroll
        for (int s = 0; s < 4; ++s)
            #pragma unroll
            for (int r = 0; r < 4; ++r) {
                float v = acc[s][nt][r];
                s_ += v; q_ += v*v;
            }
        atomicAdd(&sred[nt*16 + l15], s_);
        atomicAdd(&sred[64 + nt*16 + l15], q_);
    }
    __syncthreads();
    if (t < 128) atomicAdd(&sums[t], sred[t]);
}

// ---------------- BN scale/bias ----------------
__global__ void finalize_kernel(const float* __restrict__ sums, const float* __restrict__ gamma,
                                const float* __restrict__ beta, float* __restrict__ ab, float invn) {
    int c = threadIdx.x;
    if (c < 64) {
        float mean = sums[c] * invn;
        float var  = sums[64 + c] * invn - mean*mean;
        float a = gamma[c] * rsqrtf(var + 1e-5f);
        ab[c] = a;
        ab[64 + c] = beta[c] - mean * a;
    }
}

// ---------------- BN1 + ReLU in place on y1 (bf16) ----------------
__global__ __launch_bounds__(256)
void bnrelu_kernel(unsigned short* __restrict__ y, const float* __restrict__ ab, int n4) {
    int i = blockIdx.x * blockDim.x + threadIdx.x;
    int stride = gridDim.x * blockDim.x;
    for (; i < n4; i += stride) {
        uint2 v = ((const uint2*)y)[i];
        int c0 = (i*4) & 63;
        float f0 = fmaxf(ab[c0]   * bf2f((unsigned short)(v.x & 0xffffu)) + ab[64 + c0],   0.f);
        float f1 = fmaxf(ab[c0+1] * bf2f((unsigned short)(v.x >> 16))     + ab[64 + c0+1], 0.f);
        float f2 = fmaxf(ab[c0+2] * bf2f((unsigned short)(v.y & 0xffffu)) + ab[64 + c0+2], 0.f);
        float f3 = fmaxf(ab[c0+3] * bf2f((unsigned short)(v.y >> 16))     + ab[64 + c0+3], 0.f);
        uint2 o;
        o.x = (unsigned int)f2bf(f0) | ((unsigned int)f2bf(f1) << 16);
        o.y = (unsigned int)f2bf(f2) | ((unsigned int)f2bf(f3) << 16);
        ((uint2*)y)[i] = o;
    }
}

// ---------------- epilogue: BN2 + identity + relu -> fp32 ----------------
__global__ __launch_bounds__(256)
void final_kernel(const unsigned short* __restrict__ y2, const float* __restrict__ feat,
                  const float* __restrict__ ab, float* __restrict__ out, int ntot2) {
    int i = blockIdx.x * blockDim.x + threadIdx.x;
    int stride = gridDim.x * blockDim.x;
    for (; i < ntot2; i += stride) {
        unsigned int v = ((const unsigned int*)y2)[i];
        int c0 = (i*2) & 63;
        float2 f = ((const float2*)feat)[i];
        float r0 = fmaxf(ab[c0]   * bf2f((unsigned short)(v & 0xffffu)) + ab[64 + c0]   + f.x, 0.f);
        float r1 = fmaxf(ab[c0+1] * bf2f((unsigned short)(v >> 16))     + ab[64 + c0+1] + f.y, 0.f);
        ((float2*)out)[i] = make_float2(r0, r1);
    }
}

extern "C" void kernel_launch(void* const* d_in, const int* in_sizes, int n_in,
                              void* d_out, int out_size, void* d_ws, size_t ws_size,
                              hipStream_t stream) {
    const float* features = (const float*)d_in[0];
    const int*   nbr      = (const int*)d_in[1];
    const float* valid    = (const float*)d_in[2];
    const float* W1       = (const float*)d_in[3];
    const float* gamma1   = (const float*)d_in[4];
    const float* beta1    = (const float*)d_in[5];
    const float* W2       = (const float*)d_in[6];
    const float* gamma2   = (const float*)d_in[7];
    const float* beta2    = (const float*)d_in[8];
    float* out = (float*)d_out;

    int nvox  = in_sizes[0] / 64;                 // 500000
    int nvoxp = (nvox + 255) & ~255;              // 500224 (pad to block multiple)
    size_t featB = (size_t)nvox * 64 * 2;         // 64 MB bf16 feature map

    // d_out doubles as scratch until final_kernel overwrites all of it:
    //   [0, featB)        xb (bf16 features)
    //   [featB, 2*featB)  y1 (conv1 out, bf16; BN1+ReLU applied in place)
    char* ob = (char*)d_out;
    unsigned short* xb = (unsigned short*)ob;
    unsigned short* y1 = (unsigned short*)(ob + featB);

    // d_ws (~118.6 MB):
    //   [0, 2048)      stats: sums1, sums2, ab1, ab2 (128 floats each)
    //   [2048, 2176)   zero page (128 B)
    //   [4096, ..)     Wp1, Wp2 (216 KB each)
    //   [512K, +54MB)  enc (27 * nvoxp ints)
    //   then           y2 (bf16)
    char* ws = (char*)d_ws;
    float* stats = (float*)ws;
    float* sums1 = stats;
    float* sums2 = stats + 128;
    float* ab1   = stats + 256;
    float* ab2   = stats + 384;
    const unsigned short* zrow = (const unsigned short*)(ws + 2048);
    unsigned short* Wp1 = (unsigned short*)(ws + 4096);
    unsigned short* Wp2 = (unsigned short*)(ws + 4096 + 221184);
    int* enc = (int*)(ws + 524288);
    size_t encB = (size_t)27 * nvoxp * 4;          // 54,024,192
    unsigned short* y2 = (unsigned short*)(ws + 524288 + encB);

    hipMemsetAsync(ws, 0, 4096, stream);           // stats + zero page

    convert_bf16<<<2048, 256, 0, stream>>>(features, xb, nvox * 16);
    pack_w<<<54, 256, 0, stream>>>(W1, W2, Wp1, Wp2);
    dim3 eg(nvoxp / 256, 27);
    encode_kernel<<<eg, 256, 0, stream>>>(nbr, valid, enc, nvox, nvoxp);

    int convGrid = nvoxp / 256;   // 1954
    conv_kernel<<<convGrid, 256, 0, stream>>>(xb, enc, Wp1, zrow, y1, sums1, nvox, nvoxp);
    finalize_kernel<<<1, 64, 0, stream>>>(sums1, gamma1, beta1, ab1, 1.0f / nvox);
    bnrelu_kernel<<<2048, 256, 0, stream>>>(y1, ab1, nvox * 16);
    conv_kernel<<<convGrid, 256, 0, stream>>>(y1, enc, Wp2, zrow, y2, sums2, nvox, nvoxp);
    finalize_kernel<<<1, 64, 0, stream>>>(sums2, gamma2, beta2, ab2, 1.0f / nvox);
    final_kernel<<<4096, 256, 0, stream>>>(y2, features, ab2, out, nvox * 32);
}